// Round 1
// baseline (411.574 us; speedup 1.0000x reference)
//
#include <hip/hip_runtime.h>
#include <math.h>

#define B_ 64
#define T_ 1000
#define C_ 128
#define L_ 100
#define S_ 201        // 2*L+1
#define BLANK 127     // C-1
#define NEGF (-1e30f)

__global__ __launch_bounds__(256) void ctc_loss_kernel(
    const int* __restrict__ y_true,      // [B, L]
    const float* __restrict__ y_pred,    // [B, T, C] softmax probs
    const int* __restrict__ in_len,      // [B]
    const int* __restrict__ lab_len,     // [B]
    float* __restrict__ out)             // [B]
{
    const int b   = blockIdx.x;
    const int tid = threadIdx.x;

    __shared__ float alpha[2][S_];
    __shared__ float lp[C_];
    __shared__ int   ext[S_];
    __shared__ int   skip[S_];

    // Build extended label sequence + skip mask.
    // ext: blank, l0, blank, l1, ..., blank.  skip[s] = odd s && label[k]!=label[k-1]
    if (tid < S_) {
        int e, sk;
        if (tid & 1) {
            int k   = tid >> 1;
            e       = y_true[b * L_ + k];
            int em2 = (k == 0) ? BLANK : y_true[b * L_ + k - 1];
            sk      = (e != em2);   // labels are < 127, never equal blank
        } else {
            e  = BLANK;
            sk = 0;
        }
        ext[tid]  = e;
        skip[tid] = sk;
    }

    const int T_eff = min(T_, in_len[b]);   // alpha frozen for t >= in_len

    // ---- t = 0 ----
    float yv = 0.f;
    if (tid < C_) yv = y_pred[(b * T_ + 0) * C_ + tid];
    __syncthreads();   // ext/skip ready
    if (tid < C_) lp[tid] = logf(yv + 1e-7f);
    __syncthreads();   // lp ready
    if (tid < S_) alpha[0][tid] = (tid < 2) ? lp[ext[tid]] : NEGF;

    // prefetch frame t=1
    if (tid < C_ && T_eff > 1) yv = y_pred[(b * T_ + 1) * C_ + tid];

    int cur = 0;
    for (int t = 1; t < T_eff; ++t) {
        __syncthreads();   // prev iter's lp reads + alpha writes done
        if (tid < C_) lp[tid] = logf(yv + 1e-7f);
        // prefetch next frame while this step computes
        if (tid < C_ && t + 1 < T_eff) yv = y_pred[(b * T_ + t + 1) * C_ + tid];
        __syncthreads();   // lp visible
        if (tid < S_) {
            float a  = alpha[cur][tid];
            float a1 = (tid >= 1) ? alpha[cur][tid - 1] : NEGF;
            float a2 = (tid >= 2 && skip[tid]) ? alpha[cur][tid - 2] : NEGF;
            float m  = fmaxf(a, fmaxf(a1, a2));
            float r  = m + logf(expf(a - m) + expf(a1 - m) + expf(a2 - m));
            alpha[cur ^ 1][tid] = r + lp[ext[tid]];
        }
        cur ^= 1;
    }
    __syncthreads();

    if (tid == 0) {
        int   ll     = lab_len[b];
        float a_last = alpha[cur][2 * ll];
        float a_prev = alpha[cur][2 * ll - 1];
        float m = fmaxf(a_last, a_prev);
        float r = m + logf(expf(a_last - m) + expf(a_prev - m));
        out[b] = -r;
    }
}

extern "C" void kernel_launch(void* const* d_in, const int* in_sizes, int n_in,
                              void* d_out, int out_size, void* d_ws, size_t ws_size,
                              hipStream_t stream) {
    const int*   y_true  = (const int*)d_in[0];
    const float* y_pred  = (const float*)d_in[1];
    const int*   in_len  = (const int*)d_in[2];
    const int*   lab_len = (const int*)d_in[3];
    float*       out     = (float*)d_out;

    ctc_loss_kernel<<<B_, 256, 0, stream>>>(y_true, y_pred, in_len, lab_len, out);
}

// Round 3
// 188.085 us; speedup vs baseline: 2.1882x; 2.1882x over previous
//
#include <hip/hip_runtime.h>

#define B_ 64
#define T_ 1000
#define C_ 128
#define L_ 100
#define S_ 201        // 2*L+1
#define SP_ 204       // padded row length (multiple of 4)
#define RW_ (SP_ / 4) // 51 float4 per row
#define BLANK 127     // C-1
#define NEGF (-1e30f)
#define LN2F 0.69314718055994530942f

__device__ __forceinline__ float fexp2(float x) { return __builtin_amdgcn_exp2f(x); }
__device__ __forceinline__ float flog2(float x) { return __builtin_amdgcn_logf(x); }

// ---------------- Kernel 1: parallel gather + log2 ----------------
// lp2[(b*T + t)*SP_ + s] = log2(y_pred[b][t][ext[s]] + 1e-7), NEG for padding
__global__ __launch_bounds__(256) void ctc_gather_kernel(
    const int* __restrict__ y_true,
    const float* __restrict__ y_pred,
    float* __restrict__ lp2)
{
    const int total = B_ * T_ * SP_;
    for (int idx = blockIdx.x * 256 + threadIdx.x; idx < total;
         idx += gridDim.x * 256) {
        int row = idx / SP_;            // b*T + t  (magic-mul div)
        int s   = idx - row * SP_;
        float v;
        if (s >= S_) {
            v = NEGF;
        } else {
            int b = row / T_;
            int e = (s & 1) ? y_true[b * L_ + (s >> 1)] : BLANK;
            v = flog2(y_pred[(size_t)row * C_ + e] + 1e-7f);
        }
        lp2[idx] = v;
    }
}

// ---------------- Kernel 2: 1-wave register recurrence ----------------
// Lane l owns extended positions 4l..4l+3; alpha in registers, log2 domain.
__global__ __launch_bounds__(64) void ctc_seq_kernel(
    const float* __restrict__ lp2,
    const int* __restrict__ y_true,
    const int* __restrict__ in_len,
    const int* __restrict__ lab_len,
    float* __restrict__ out)
{
    const int b = blockIdx.x;
    const int l = threadIdx.x;
    const int p0 = l * 4;

    // skip masks for the two odd positions this lane owns (p0+1, p0+3)
    bool sk1 = false, sk3 = false;
    {
        int k1 = (p0 + 1) >> 1;   // = 2l
        int k3 = (p0 + 3) >> 1;   // = 2l+1
        if (k1 < L_) sk1 = (k1 == 0) || (y_true[b * L_ + k1] != y_true[b * L_ + k1 - 1]);
        if (k3 < L_) sk3 = (k3 == 0) || (y_true[b * L_ + k3] != y_true[b * L_ + k3 - 1]);
    }

    const int Teff = min(T_, in_len[b]);
    const float4* rows = (const float4*)(lp2 + (size_t)b * T_ * SP_);
    const bool ld = (l < RW_);

    auto ldrow = [&](int t) -> float4 {
        t = min(t, Teff - 1);                 // clamp: pipeline overshoot safe
        if (ld) return rows[t * RW_ + l];
        return make_float4(NEGF, NEGF, NEGF, NEGF);
    };

    auto lse2 = [](float x, float y) {
        float m = fmaxf(x, y);
        return m + flog2(fexp2(x - m) + fexp2(y - m));
    };
    auto lse3 = [](float x, float y, float z) {
        float m = fmaxf(x, fmaxf(y, z));
        return m + flog2(fexp2(x - m) + fexp2(y - m) + fexp2(z - m));
    };

    // t = 0 init
    float4 lp0 = ldrow(0);
    float a0 = (p0 + 0 < 2) ? lp0.x : NEGF;
    float a1 = (p0 + 1 < 2) ? lp0.y : NEGF;
    float a2 = NEGF;
    float a3 = NEGF;

    auto step = [&](float4 lp) {
        float s3  = __shfl_up(a3, 1);           // alpha[p0-1] from lane l-1
        float p_1 = (l == 0) ? NEGF : s3;
        // even positions (j=0,2): blank, skip never applies -> 2-way LSE
        // odd positions  (j=1,3): 3-way LSE with skip-gated third term
        float n0 = lse2(a0, p_1) + lp.x;
        float n1 = lse3(a1, a0, sk1 ? p_1 : NEGF) + lp.y;
        float n2 = lse2(a2, a1) + lp.z;
        float n3 = lse3(a3, a2, sk3 ? a1 : NEGF) + lp.w;
        a0 = n0; a1 = n1; a2 = n2; a3 = n3;
    };

    // 4-deep software pipeline over frames (named regs, no runtime indexing)
    float4 f0 = ldrow(1), f1 = ldrow(2), f2 = ldrow(3), f3 = ldrow(4);
    int t = 1;
    for (; t + 4 <= Teff; t += 4) {
        step(f0); f0 = ldrow(t + 4);
        step(f1); f1 = ldrow(t + 5);
        step(f2); f2 = ldrow(t + 6);
        step(f3); f3 = ldrow(t + 7);
    }
    if (t < Teff) { step(f0); ++t; }
    if (t < Teff) { step(f1); ++t; }
    if (t < Teff) { step(f2); ++t; }

    // final: -logaddexp(alpha[2ll], alpha[2ll-1])  (convert log2 -> ln)
    int ll = lab_len[b];
    int pa = 2 * ll,     la  = pa >> 2, ja = pa & 3;
    int pb = 2 * ll - 1, lb_ = pb >> 2, jb = pb & 3;
    float ca0 = __shfl(a0, la), ca1 = __shfl(a1, la),
          ca2 = __shfl(a2, la), ca3 = __shfl(a3, la);
    float va = (ja == 0) ? ca0 : (ja == 1) ? ca1 : (ja == 2) ? ca2 : ca3;
    float cb0 = __shfl(a0, lb_), cb1 = __shfl(a1, lb_),
          cb2 = __shfl(a2, lb_), cb3 = __shfl(a3, lb_);
    float vb = (jb == 0) ? cb0 : (jb == 1) ? cb1 : (jb == 2) ? cb2 : cb3;
    if (l == 0) {
        float m = fmaxf(va, vb);
        float r = m + flog2(fexp2(va - m) + fexp2(vb - m));
        out[b] = -r * LN2F;
    }
}

// ---------------- Round-1 fallback (small ws_size) ----------------
__global__ __launch_bounds__(256) void ctc_loss_kernel(
    const int* __restrict__ y_true, const float* __restrict__ y_pred,
    const int* __restrict__ in_len, const int* __restrict__ lab_len,
    float* __restrict__ out)
{
    const int b   = blockIdx.x;
    const int tid = threadIdx.x;
    __shared__ float alpha[2][S_];
    __shared__ float lp[C_];
    __shared__ int   ext[S_];
    __shared__ int   skip[S_];
    if (tid < S_) {
        int e, sk;
        if (tid & 1) {
            int k   = tid >> 1;
            e       = y_true[b * L_ + k];
            int em2 = (k == 0) ? BLANK : y_true[b * L_ + k - 1];
            sk      = (e != em2);
        } else { e = BLANK; sk = 0; }
        ext[tid]  = e;
        skip[tid] = sk;
    }
    const int T_eff = min(T_, in_len[b]);
    float yv = 0.f;
    if (tid < C_) yv = y_pred[(b * T_ + 0) * C_ + tid];
    __syncthreads();
    if (tid < C_) lp[tid] = flog2(yv + 1e-7f) * LN2F;
    __syncthreads();
    if (tid < S_) alpha[0][tid] = (tid < 2) ? lp[ext[tid]] : NEGF;
    if (tid < C_ && T_eff > 1) yv = y_pred[(b * T_ + 1) * C_ + tid];
    int cur = 0;
    for (int t = 1; t < T_eff; ++t) {
        __syncthreads();
        if (tid < C_) lp[tid] = flog2(yv + 1e-7f) * LN2F;
        if (tid < C_ && t + 1 < T_eff) yv = y_pred[(b * T_ + t + 1) * C_ + tid];
        __syncthreads();
        if (tid < S_) {
            float a  = alpha[cur][tid];
            float a1 = (tid >= 1) ? alpha[cur][tid - 1] : NEGF;
            float a2 = (tid >= 2 && skip[tid]) ? alpha[cur][tid - 2] : NEGF;
            float m  = fmaxf(a, fmaxf(a1, a2));
            float r  = m + flog2(fexp2((a - m) * (1.0f/LN2F)) + fexp2((a1 - m) * (1.0f/LN2F)) + fexp2((a2 - m) * (1.0f/LN2F))) * LN2F;
            alpha[cur ^ 1][tid] = r + lp[ext[tid]];
        }
        cur ^= 1;
    }
    __syncthreads();
    if (tid == 0) {
        int   ll     = lab_len[b];
        float a_last = alpha[cur][2 * ll];
        float a_prev = alpha[cur][2 * ll - 1];
        float m = fmaxf(a_last, a_prev);
        out[b] = -(m + flog2(fexp2((a_last - m) * (1.0f/LN2F)) + fexp2((a_prev - m) * (1.0f/LN2F))) * LN2F);
    }
}

extern "C" void kernel_launch(void* const* d_in, const int* in_sizes, int n_in,
                              void* d_out, int out_size, void* d_ws, size_t ws_size,
                              hipStream_t stream) {
    const int*   y_true  = (const int*)d_in[0];
    const float* y_pred  = (const float*)d_in[1];
    const int*   in_len  = (const int*)d_in[2];
    const int*   lab_len = (const int*)d_in[3];
    float*       out     = (float*)d_out;

    const size_t need = (size_t)B_ * T_ * SP_ * sizeof(float);
    if (ws_size >= need) {
        ctc_gather_kernel<<<4096, 256, 0, stream>>>(y_true, y_pred, (float*)d_ws);
        ctc_seq_kernel<<<B_, 64, 0, stream>>>((const float*)d_ws, y_true,
                                              in_len, lab_len, out);
    } else {
        ctc_loss_kernel<<<B_, 256, 0, stream>>>(y_true, y_pred, in_len, lab_len, out);
    }
}

// Round 5
// 95.977 us; speedup vs baseline: 4.2883x; 1.9597x over previous
//
#include <hip/hip_runtime.h>

#define B_ 64
#define T_ 1000
#define C_ 128
#define L_ 100
#define BLANK 127     // C-1
#define LN2F 0.69314718055994530942f

__device__ __forceinline__ float flog2(float x) { return __builtin_amdgcn_logf(x); }

// One wave per batch element. Lane l owns extended-label positions 4l..4l+3.
// Linear-domain forward recurrence, alpha in f64 (2046-bit dynamic range
// absorbs cross-position spread that killed the f32 version), probs in f32.
// Uniform power-of-2 rescale every 16 steps via u32-hi-word max butterfly.
__global__ __launch_bounds__(64) void ctc_f64_kernel(
    const int* __restrict__ y_true,      // [B, L]
    const float* __restrict__ y_pred,    // [B, T, C]
    const int* __restrict__ in_len,      // [B]
    const int* __restrict__ lab_len,     // [B]
    float* __restrict__ out)             // [B]
{
    const int b = blockIdx.x;
    const int l = threadIdx.x;

    // labels for this lane's two odd positions (4l+1 -> k1=2l, 4l+3 -> k3=2l+1)
    const int k1 = min(2 * l, L_ - 1);
    const int k3 = min(2 * l + 1, L_ - 1);
    const int e1 = y_true[b * L_ + k1];
    const int e3 = y_true[b * L_ + k3];
    // skip masks: s=1 (k==0) always allowed; else label[k] != label[k-1]
    const double m1 = (k1 == 0 || e1 != y_true[b * L_ + k1 - 1]) ? 1.0 : 0.0;
    const double m3 = (e3 != y_true[b * L_ + k3 - 1]) ? 1.0 : 0.0;   // k3 >= 1

    const int Teff = min(T_, in_len[b]);
    const float* rowb = y_pred + (size_t)b * T_ * C_;

#define LD3(t_, PB, P1, P3) { int tc_ = min((t_), Teff - 1); \
    const float* r_ = rowb + tc_ * C_; \
    PB = r_[BLANK] + 1e-7f; P1 = r_[e1] + 1e-7f; P3 = r_[e3] + 1e-7f; }

    // t = 0: alpha[0] = p_blank, alpha[1] = p_label0, rest 0
    double a0, a1, a2 = 0.0, a3 = 0.0;
    { float pb, p1, p3; LD3(0, pb, p1, p3);
      a0 = (l == 0) ? (double)pb : 0.0;
      a1 = (l == 0) ? (double)p1 : 0.0; }

    int E = 0;   // accumulated base-2 exponent (wave-uniform)

#define STEP(PB, P1, P3) { \
    double s3_  = __shfl_up(a3, 1); \
    double pm1_ = (l == 0) ? 0.0 : s3_;        /* alpha[4l-1] */ \
    double n0_ = (a0 + pm1_) * (double)(PB); \
    double n1_ = (a1 + a0 + m1 * pm1_) * (double)(P1); \
    double n2_ = (a2 + a1) * (double)(PB); \
    double n3_ = (a3 + a2 + m3 * a1) * (double)(P3); \
    a0 = n0_; a1 = n1_; a2 = n2_; a3 = n3_; }

// max of positive doubles == max of hi-32 words as u32 (monotonic encoding)
#define RESCALE() { \
    unsigned u_ = max(max((unsigned)__double2hiint(a0), (unsigned)__double2hiint(a1)), \
                      max((unsigned)__double2hiint(a2), (unsigned)__double2hiint(a3))); \
    u_ = max(u_, (unsigned)__shfl_xor((int)u_, 1)); \
    u_ = max(u_, (unsigned)__shfl_xor((int)u_, 2)); \
    u_ = max(u_, (unsigned)__shfl_xor((int)u_, 4)); \
    u_ = max(u_, (unsigned)__shfl_xor((int)u_, 8)); \
    u_ = max(u_, (unsigned)__shfl_xor((int)u_, 16)); \
    u_ = max(u_, (unsigned)__shfl_xor((int)u_, 32)); \
    int kk_ = (int)(u_ >> 20); \
    if (kk_ > 0) { \
        double f_ = __hiloint2double((2046 - kk_) << 20, 0);  /* 2^(1023-kk) exact */ \
        a0 *= f_; a1 *= f_; a2 *= f_; a3 *= f_; \
        E += kk_ - 1023; } }

    // 16-frame software pipeline, named registers only (rule: no runtime indexing)
    float pb0,p10,p30, pb1,p11,p31, pb2,p12,p32, pb3,p13,p33,
          pb4,p14,p34, pb5,p15,p35, pb6,p16,p36, pb7,p17,p37,
          pb8,p18,p38, pb9,p19,p39, pbA,p1A,p3A, pbB,p1B,p3B,
          pbC,p1C,p3C, pbD,p1D,p3D, pbE,p1E,p3E, pbF,p1F,p3F;
    LD3(1,  pb0,p10,p30); LD3(2,  pb1,p11,p31); LD3(3,  pb2,p12,p32); LD3(4,  pb3,p13,p33);
    LD3(5,  pb4,p14,p34); LD3(6,  pb5,p15,p35); LD3(7,  pb6,p16,p36); LD3(8,  pb7,p17,p37);
    LD3(9,  pb8,p18,p38); LD3(10, pb9,p19,p39); LD3(11, pbA,p1A,p3A); LD3(12, pbB,p1B,p3B);
    LD3(13, pbC,p1C,p3C); LD3(14, pbD,p1D,p3D); LD3(15, pbE,p1E,p3E); LD3(16, pbF,p1F,p3F);

    int t = 1;
    for (; t + 16 <= Teff; t += 16) {
        STEP(pb0,p10,p30); LD3(t + 16, pb0,p10,p30);
        STEP(pb1,p11,p31); LD3(t + 17, pb1,p11,p31);
        STEP(pb2,p12,p32); LD3(t + 18, pb2,p12,p32);
        STEP(pb3,p13,p33); LD3(t + 19, pb3,p13,p33);
        STEP(pb4,p14,p34); LD3(t + 20, pb4,p14,p34);
        STEP(pb5,p15,p35); LD3(t + 21, pb5,p15,p35);
        STEP(pb6,p16,p36); LD3(t + 22, pb6,p16,p36);
        STEP(pb7,p17,p37); LD3(t + 23, pb7,p17,p37);
        STEP(pb8,p18,p38); LD3(t + 24, pb8,p18,p38);
        STEP(pb9,p19,p39); LD3(t + 25, pb9,p19,p39);
        STEP(pbA,p1A,p3A); LD3(t + 26, pbA,p1A,p3A);
        STEP(pbB,p1B,p3B); LD3(t + 27, pbB,p1B,p3B);
        STEP(pbC,p1C,p3C); LD3(t + 28, pbC,p1C,p3C);
        STEP(pbD,p1D,p3D); LD3(t + 29, pbD,p1D,p3D);
        STEP(pbE,p1E,p3E); LD3(t + 30, pbE,p1E,p3E);
        STEP(pbF,p1F,p3F); LD3(t + 31, pbF,p1F,p3F);
        RESCALE();
    }
    // tail: registers f_i hold rows t+i (clamped); <= 15 steps, f64 range safe
    if (t < Teff) { STEP(pb0,p10,p30); ++t; }
    if (t < Teff) { STEP(pb1,p11,p31); ++t; }
    if (t < Teff) { STEP(pb2,p12,p32); ++t; }
    if (t < Teff) { STEP(pb3,p13,p33); ++t; }
    if (t < Teff) { STEP(pb4,p14,p34); ++t; }
    if (t < Teff) { STEP(pb5,p15,p35); ++t; }
    if (t < Teff) { STEP(pb6,p16,p36); ++t; }
    if (t < Teff) { STEP(pb7,p17,p37); ++t; }
    if (t < Teff) { STEP(pb8,p18,p38); ++t; }
    if (t < Teff) { STEP(pb9,p19,p39); ++t; }
    if (t < Teff) { STEP(pbA,p1A,p3A); ++t; }
    if (t < Teff) { STEP(pbB,p1B,p3B); ++t; }
    if (t < Teff) { STEP(pbC,p1C,p3C); ++t; }
    if (t < Teff) { STEP(pbD,p1D,p3D); ++t; }
    if (t < Teff) { STEP(pbE,p1E,p3E); ++t; }

    // final: -ln(alpha[2ll] + alpha[2ll-1]), exponent-adjusted
    const int llb = lab_len[b];
    const int pa  = 2 * llb;      // even -> a0 or a2
    const int qa  = pa >> 2;
    double va = ((pa & 3) == 0) ? __shfl(a0, qa) : __shfl(a2, qa);
    const int pq  = 2 * llb - 1;  // odd -> a1 or a3
    const int qb  = pq >> 2;
    double vb = ((pq & 3) == 1) ? __shfl(a1, qb) : __shfl(a3, qb);
    if (l == 0) {
        double s  = va + vb;                       // true alpha * 2^-E
        int hi    = __double2hiint(s);
        int lo    = __double2loint(s);
        int ke    = (hi >> 20) & 0x7FF;
        double mant = __hiloint2double((hi & 0x000FFFFF) | (1023 << 20), lo); // [1,2)
        float r = flog2((float)mant) + (float)(ke - 1023 + E);
        out[b] = -r * LN2F;
    }
}

extern "C" void kernel_launch(void* const* d_in, const int* in_sizes, int n_in,
                              void* d_out, int out_size, void* d_ws, size_t ws_size,
                              hipStream_t stream) {
    const int*   y_true  = (const int*)d_in[0];
    const float* y_pred  = (const float*)d_in[1];
    const int*   in_len  = (const int*)d_in[2];
    const int*   lab_len = (const int*)d_in[3];
    float*       out     = (float*)d_out;

    ctc_f64_kernel<<<B_, 64, 0, stream>>>(y_true, y_pred, in_len, lab_len, out);
}

// Round 8
// 71.492 us; speedup vs baseline: 5.7569x; 1.3425x over previous
//
#include <hip/hip_runtime.h>

#define B_ 64
#define T_ 1000
#define C_ 128
#define L_ 100
#define BLANK 127     // C-1
#define LN2F 0.69314718055994530942f

__device__ __forceinline__ float flog2(float x) { return __builtin_amdgcn_logf(x); }

// DPP controls (gfx9/CDNA)
#define DPP_ROW_SHR1   0x111
#define DPP_ROW_SHR2   0x112
#define DPP_ROW_SHR4   0x114
#define DPP_ROW_SHR8   0x118
#define DPP_WAVE_SHR1  0x138   // wave-level: lane i <- lane i-1, crosses rows

template <int CTRL>
__device__ __forceinline__ int dpp_mov(int src) {
    // old = 0, all rows/banks, bound_ctrl=false -> invalid-source lanes get old (0)
    return __builtin_amdgcn_update_dpp(0, src, CTRL, 0xF, 0xF, false);
}

// One wave per batch element. Lane l owns extended-label positions 4l..4l+3.
// Linear-domain forward recurrence in f64 (validated R5); neighbor exchange via
// wave_shr:1 DPP (VALU pipe, no LDS), rescale max via row_shr scan + readlanes.
__global__ __launch_bounds__(64) void ctc_dpp_kernel(
    const int* __restrict__ y_true,      // [B, L]
    const float* __restrict__ y_pred,    // [B, T, C]
    const int* __restrict__ in_len,      // [B]
    const int* __restrict__ lab_len,     // [B]
    float* __restrict__ out)             // [B]
{
    const int b = blockIdx.x;
    const int l = threadIdx.x;

    // labels for this lane's two odd positions (4l+1 -> k1=2l, 4l+3 -> k3=2l+1)
    const int k1 = min(2 * l, L_ - 1);
    const int k3 = min(2 * l + 1, L_ - 1);
    const int e1 = y_true[b * L_ + k1];
    const int e3 = y_true[b * L_ + k3];
    const double m1 = (k1 == 0 || e1 != y_true[b * L_ + k1 - 1]) ? 1.0 : 0.0;
    const double m3 = (e3 != y_true[b * L_ + k3 - 1]) ? 1.0 : 0.0;   // k3 >= 1

    const int Teff = min(T_, in_len[b]);
    const float* rowb = y_pred + (size_t)b * T_ * C_;

#define LD3(t_, PB, P1, P3) { int tc_ = min((t_), Teff - 1); \
    const float* r_ = rowb + tc_ * C_; \
    PB = r_[BLANK] + 1e-7f; P1 = r_[e1] + 1e-7f; P3 = r_[e3] + 1e-7f; }

    // t = 0: alpha[0] = p_blank, alpha[1] = p_label0, rest 0
    double a0, a1, a2 = 0.0, a3 = 0.0;
    { float pb, p1, p3; LD3(0, pb, p1, p3);
      a0 = (l == 0) ? (double)pb : 0.0;
      a1 = (l == 0) ? (double)p1 : 0.0; }

    int E = 0;   // accumulated base-2 exponent (wave-uniform)

// pm1 = alpha[4l-1] (a3 of lane l-1), 0 for lane 0 — one wave-level DPP shift.
#define STEP(PB, P1, P3) { \
    int slo_ = dpp_mov<DPP_WAVE_SHR1>(__double2loint(a3)); \
    int shi_ = dpp_mov<DPP_WAVE_SHR1>(__double2hiint(a3)); \
    double pm1_ = __hiloint2double(shi_, slo_); \
    double n0_ = (a0 + pm1_) * (double)(PB); \
    double n1_ = (a1 + a0 + m1 * pm1_) * (double)(P1); \
    double n2_ = (a2 + a1) * (double)(PB); \
    double n3_ = (a3 + a2 + m3 * a1) * (double)(P3); \
    a0 = n0_; a1 = n1_; a2 = n2_; a3 = n3_; }

// wave-max of positive doubles via u32 hi-words: row_shr max-scan (verified
// direction: lane i <- lane i-N) then 4 readlanes at row ends + scalar max.
#define DPPMAX(u_, ctrl_) { unsigned t_ = (unsigned)dpp_mov<ctrl_>((int)(u_)); \
    u_ = max(u_, t_); }
#define RESCALE() { \
    unsigned u_ = max(max((unsigned)__double2hiint(a0), (unsigned)__double2hiint(a1)), \
                      max((unsigned)__double2hiint(a2), (unsigned)__double2hiint(a3))); \
    DPPMAX(u_, DPP_ROW_SHR1); \
    DPPMAX(u_, DPP_ROW_SHR2); \
    DPPMAX(u_, DPP_ROW_SHR4); \
    DPPMAX(u_, DPP_ROW_SHR8); \
    unsigned g_ = max(max((unsigned)__builtin_amdgcn_readlane((int)u_, 15), \
                          (unsigned)__builtin_amdgcn_readlane((int)u_, 31)), \
                      max((unsigned)__builtin_amdgcn_readlane((int)u_, 47), \
                          (unsigned)__builtin_amdgcn_readlane((int)u_, 63))); \
    int kk_ = (int)(g_ >> 20); \
    if (kk_ > 0) { \
        double f_ = __hiloint2double((2046 - kk_) << 20, 0);  /* 2^(1023-kk) exact */ \
        a0 *= f_; a1 *= f_; a2 *= f_; a3 *= f_; \
        E += kk_ - 1023; } }

    // 16-frame software pipeline, named registers only (no runtime indexing)
    float pb0,p10,p30, pb1,p11,p31, pb2,p12,p32, pb3,p13,p33,
          pb4,p14,p34, pb5,p15,p35, pb6,p16,p36, pb7,p17,p37,
          pb8,p18,p38, pb9,p19,p39, pbA,p1A,p3A, pbB,p1B,p3B,
          pbC,p1C,p3C, pbD,p1D,p3D, pbE,p1E,p3E, pbF,p1F,p3F;
    LD3(1,  pb0,p10,p30); LD3(2,  pb1,p11,p31); LD3(3,  pb2,p12,p32); LD3(4,  pb3,p13,p33);
    LD3(5,  pb4,p14,p34); LD3(6,  pb5,p15,p35); LD3(7,  pb6,p16,p36); LD3(8,  pb7,p17,p37);
    LD3(9,  pb8,p18,p38); LD3(10, pb9,p19,p39); LD3(11, pbA,p1A,p3A); LD3(12, pbB,p1B,p3B);
    LD3(13, pbC,p1C,p3C); LD3(14, pbD,p1D,p3D); LD3(15, pbE,p1E,p3E); LD3(16, pbF,p1F,p3F);

    int t = 1;
    for (; t + 16 <= Teff; t += 16) {
        STEP(pb0,p10,p30); LD3(t + 16, pb0,p10,p30);
        STEP(pb1,p11,p31); LD3(t + 17, pb1,p11,p31);
        STEP(pb2,p12,p32); LD3(t + 18, pb2,p12,p32);
        STEP(pb3,p13,p33); LD3(t + 19, pb3,p13,p33);
        STEP(pb4,p14,p34); LD3(t + 20, pb4,p14,p34);
        STEP(pb5,p15,p35); LD3(t + 21, pb5,p15,p35);
        STEP(pb6,p16,p36); LD3(t + 22, pb6,p16,p36);
        STEP(pb7,p17,p37); LD3(t + 23, pb7,p17,p37);
        STEP(pb8,p18,p38); LD3(t + 24, pb8,p18,p38);
        STEP(pb9,p19,p39); LD3(t + 25, pb9,p19,p39);
        STEP(pbA,p1A,p3A); LD3(t + 26, pbA,p1A,p3A);
        STEP(pbB,p1B,p3B); LD3(t + 27, pbB,p1B,p3B);
        STEP(pbC,p1C,p3C); LD3(t + 28, pbC,p1C,p3C);
        STEP(pbD,p1D,p3D); LD3(t + 29, pbD,p1D,p3D);
        STEP(pbE,p1E,p3E); LD3(t + 30, pbE,p1E,p3E);
        STEP(pbF,p1F,p3F); LD3(t + 31, pbF,p1F,p3F);
        RESCALE();
    }
    // tail (<= 15 steps; registers hold rows t..t+14 clamped, f64 range safe)
    if (t < Teff) { STEP(pb0,p10,p30); ++t; }
    if (t < Teff) { STEP(pb1,p11,p31); ++t; }
    if (t < Teff) { STEP(pb2,p12,p32); ++t; }
    if (t < Teff) { STEP(pb3,p13,p33); ++t; }
    if (t < Teff) { STEP(pb4,p14,p34); ++t; }
    if (t < Teff) { STEP(pb5,p15,p35); ++t; }
    if (t < Teff) { STEP(pb6,p16,p36); ++t; }
    if (t < Teff) { STEP(pb7,p17,p37); ++t; }
    if (t < Teff) { STEP(pb8,p18,p38); ++t; }
    if (t < Teff) { STEP(pb9,p19,p39); ++t; }
    if (t < Teff) { STEP(pbA,p1A,p3A); ++t; }
    if (t < Teff) { STEP(pbB,p1B,p3B); ++t; }
    if (t < Teff) { STEP(pbC,p1C,p3C); ++t; }
    if (t < Teff) { STEP(pbD,p1D,p3D); ++t; }
    if (t < Teff) { STEP(pbE,p1E,p3E); ++t; }

    // final: -ln(alpha[2ll] + alpha[2ll-1]), exponent-adjusted
    const int llb = lab_len[b];
    const int pa  = 2 * llb;      // even -> a0 or a2
    const int qa  = pa >> 2;
    double va = ((pa & 3) == 0) ? __shfl(a0, qa) : __shfl(a2, qa);
    const int pq  = 2 * llb - 1;  // odd -> a1 or a3
    const int qb  = pq >> 2;
    double vb = ((pq & 3) == 1) ? __shfl(a1, qb) : __shfl(a3, qb);
    if (l == 0) {
        double s  = va + vb;                       // true alpha * 2^-E
        int hi    = __double2hiint(s);
        int lo    = __double2loint(s);
        int ke    = (hi >> 20) & 0x7FF;
        double mant = __hiloint2double((hi & 0x000FFFFF) | (1023 << 20), lo); // [1,2)
        float r = flog2((float)mant) + (float)(ke - 1023 + E);
        out[b] = -r * LN2F;
    }
}

extern "C" void kernel_launch(void* const* d_in, const int* in_sizes, int n_in,
                              void* d_out, int out_size, void* d_ws, size_t ws_size,
                              hipStream_t stream) {
    const int*   y_true  = (const int*)d_in[0];
    const float* y_pred  = (const float*)d_in[1];
    const int*   in_len  = (const int*)d_in[2];
    const int*   lab_len = (const int*)d_in[3];
    float*       out     = (float*)d_out;

    ctc_dpp_kernel<<<B_, 64, 0, stream>>>(y_true, y_pred, in_len, lab_len, out);
}